// Round 5
// baseline (99.277 us; speedup 1.0000x reference)
//
#include <hip/hip_runtime.h>
#include <math.h>

#define BB 2
#define TT 4096
#define CC 64
#define HH 4
#define DH 16
#define NROW (BB*TT)                 // 8192
#define SCALE 0.36067376022224085f   // 0.25 * log2(e)

typedef __fp16 h4 __attribute__((ext_vector_type(4)));
typedef __fp16 h2 __attribute__((ext_vector_type(2)));
typedef __fp16 h8 __attribute__((ext_vector_type(8)));
typedef float  f4 __attribute__((ext_vector_type(4)));
typedef float  f16v __attribute__((ext_vector_type(16)));

union U4H8 { uint4 u; h8 h; };
union UWH8 { unsigned u[4]; h8 h; };

// ---------------- Kernel A: qkv GEMM, D[o][r] orientation for packed stores ----------------
// 512 blocks x 256 thr: block = 16 rows; wave w -> output tiles w*3..w*3+2 (of 12)
// Q,K: [bh][T][16] f16.
// VT k16-grouped layout: [bh][chunk:64][sub:4][d:32][k16:16] f16
//   (sub = 16-k subtile within the 64-k chunk; d rows 0..15 = V^T, rows 16..31 =
//   pad with rows 16 and 20 = 1.0 so the PV 32x32x16 MFMA accumulates
//   L = sum(exp) into acc reg 8 of every lane; other pad rows = 0.)
__global__ __launch_bounds__(256) void qkv_kernel(const float* __restrict__ x,
        const float* __restrict__ w, const float* __restrict__ bias,
        __fp16* __restrict__ Q, __fp16* __restrict__ K, __fp16* __restrict__ VT) {
    __shared__ __fp16 smv[64][16];   // [h*16+d][t-col] staging for V transpose
    const int t = threadIdx.x;
    const int wave = t >> 6, lane = t & 63;
    const int lq = lane & 15, g = lane >> 4;
    const int r0 = blockIdx.x*16;
    const int b = r0 >> 12, tt0 = r0 & (TT-1);

    // B-frag (x^T): lane holds x[r0+lq][s*16 + g*4 + j]
    h4 xb[4];
    const float* xrow = x + (size_t)(r0 + lq)*CC;
    #pragma unroll
    for (int s = 0; s < 4; s++) {
        float4 xv = *(const float4*)(xrow + s*16 + g*4);
        h2 lo = __builtin_amdgcn_cvt_pkrtz(xv.x, xv.y);
        h2 hi = __builtin_amdgcn_cvt_pkrtz(xv.z, xv.w);
        xb[s] = (h4){lo.x, lo.y, hi.x, hi.y};
    }

    #pragma unroll
    for (int j = 0; j < 3; j++) {
        const int nt = wave*3 + j;       // tile: o-range [nt*16, nt*16+16)
        const int o0 = nt*16;
        const float sc = (nt < 4) ? SCALE : 1.0f;
        float4 bv = *(const float4*)(bias + o0 + g*4);
        f4 acc = {bv.x*sc, bv.y*sc, bv.z*sc, bv.w*sc};
        #pragma unroll
        for (int s = 0; s < 4; s++) {
            float4 wv = *(const float4*)(w + (size_t)(o0 + lq)*CC + s*16 + g*4);
            h2 lo = __builtin_amdgcn_cvt_pkrtz(wv.x*sc, wv.y*sc);
            h2 hi = __builtin_amdgcn_cvt_pkrtz(wv.z*sc, wv.w*sc);
            h4 af = (h4){lo.x, lo.y, hi.x, hi.y};
            acc = __builtin_amdgcn_mfma_f32_16x16x16f16(af, xb[s], acc, 0, 0, 0);
        }
        h2 plo = __builtin_amdgcn_cvt_pkrtz(acc.x, acc.y);
        h2 phi = __builtin_amdgcn_cvt_pkrtz(acc.z, acc.w);
        h4 pk = (h4){plo.x, plo.y, phi.x, phi.y};
        if (nt < 8) {
            const int part = nt >> 2, h = nt & 3;
            __fp16* dst = (part == 0) ? Q : K;
            *(h4*)(dst + ((size_t)(b*HH + h)*TT + tt0 + lq)*DH + g*4) = pk;
        } else {
            const int h = nt - 8;
            smv[h*16 + g*4 + 0][lq] = pk.x;
            smv[h*16 + g*4 + 1][lq] = pk.y;
            smv[h*16 + g*4 + 2][lq] = pk.z;
            smv[h*16 + g*4 + 3][lq] = pk.w;
        }
    }
    __syncthreads();
    if (t < 64) {                        // row (h,d): 16 t-cols = one k16 group = 32B
        const int h = t >> 4, d = t & 15;
        uint4 v0 = *(const uint4*)&smv[t][0];
        uint4 v1 = *(const uint4*)&smv[t][8];
        // tt0 is a multiple of 16 -> all 16 cols land in sub = (tt0&63)>>4, k16 0..15
        __fp16* dst = VT + (size_t)(b*HH + h)*TT*32
                        + (size_t)(tt0 >> 6)*2048           // chunk
                        + (size_t)((tt0 & 63) >> 4)*512     // sub
                        + (size_t)d*16;                     // d row
        *(uint4*)dst = v0;           // k16 0..7
        *(uint4*)(dst + 8) = v1;     // k16 8..15
        // pad row d+16: ones for d==0 (row 16) and d==4 (row 20), else zeros
        const unsigned cb = (d == 0 || d == 4) ? 0x3C003C00u : 0u;
        const uint4 cv = {cb, cb, cb, cb};
        __fp16* dst2 = dst + 16*16;  // 16 rows down within the same sub-block
        *(uint4*)dst2 = cv;
        *(uint4*)(dst2 + 8) = cv;
    }
}

// ---------------- Kernel B: flash attention, 64 q-rows/block, native 32x32x16 MFMA ----------------
// 512 blocks x 256 thr: block = (head, 64-row qtile); wave w = k-range [w*1024,(w+1)*1024)
// Identical to round-4 EXCEPT: the v_permlane32_swap_b32 asm is no longer
// `volatile`.  volatile pinned program order at 32 points per chunk, preventing
// the scheduler from software-pipelining the 4 independent S-tiles per chunk
// (each tile's S-MFMA-latency -> 16x exp2 -> pack -> swap -> PV chain was forced
// to run back-to-back = ~22K cyc/wave of exposed latency, the measured stall).
// The "+v" constraints carry full data deps, so non-volatile is semantically safe.
__global__ __launch_bounds__(256) void attn_kernel(const __fp16* __restrict__ Q,
        const __fp16* __restrict__ K, const __fp16* __restrict__ VT,
        __fp16* __restrict__ yh) {
    __shared__ float Osm[4][2][64][9];   // [ksplit][qtile][lane][reg0..7, L]
    const int t = threadIdx.x;
    const int wave = t >> 6, lane = t & 63;
    const int l31 = lane & 31, hi = lane >> 5;
    const int head = blockIdx.x >> 6;
    const int qt   = blockIdx.x & 63;
    const int q0 = qt*64;
    const __fp16* Qh = Q  + (size_t)head*TT*DH;
    const __fp16* Kh = K  + (size_t)head*TT*DH;
    const __fp16* Vh = VT + (size_t)head*TT*32;

    // Q fragments (B-operand): col q = l31, d = hi*8 + j  -> 16B loads
    U4H8 qf0, qf1;
    qf0.u = *(const uint4*)(Qh + (size_t)(q0 + l31)*DH + hi*8);
    qf1.u = *(const uint4*)(Qh + (size_t)(q0 + 32 + l31)*DH + hi*8);

    const f16v Zf = {0.f,0.f,0.f,0.f,0.f,0.f,0.f,0.f,0.f,0.f,0.f,0.f,0.f,0.f,0.f,0.f};
    f16v O0 = Zf, O1 = Zf;

    // chunk-indexed base pointers within this wave's k-range
    const __fp16* kbase = Kh + (size_t)(wave*1024 + l31)*DH + hi*8;      // + c*1024 + kt*512
    // V A-frag: lane l31 = d row, k = hi*8+j -> addr = d*16 + hi*8 (dense 1KB/wave)
    const __fp16* vbase = Vh + (size_t)(wave*16)*2048 + l31*16 + hi*8;   // + c*2048 + s*512

    const int start = (blockIdx.x*5 + wave*3) & 15;   // per-(block,wave) phase

    uint4 ka[2], va[4], kb[2], vb[4];

#define LOADC(c, KF, VF)                                                   \
    {  const size_t cc_ = (size_t)(c);                                     \
       _Pragma("unroll") for (int kt_ = 0; kt_ < 2; kt_++)                 \
           KF[kt_] = *(const uint4*)(kbase + cc_*1024 + kt_*512);          \
       _Pragma("unroll") for (int s_ = 0; s_ < 4; s_++)                    \
           VF[s_] = *(const uint4*)(vbase + cc_*2048 + s_*512);            \
    }

    LOADC(start, ka, va)

// For S-tile: W_[m] = packed f16 pair of exp2(S[2m]),exp2(S[2m+1]).
// Quad W_[4*s2..4*s2+3] covers phys k (within 16-seg): hs0 lanes {0,1,2,3,8,9,10,11},
// hs1 lanes {4,5,6,7,12,13,14,15}. permlane32_swap(x=y=W) yields x'=hs0-copy,
// y'=hs1-copy on ALL lanes; per-lane hi selects its kappa=8*hi+j slot values.
// NOTE: asm intentionally NOT volatile -- pure reg-to-reg op, deps via "+v".
#define PROC_TILE(S, O, VF)                                                        \
    {   float p_[16]; unsigned W_[8];                                              \
        _Pragma("unroll") for (int r_ = 0; r_ < 16; r_++)                          \
            p_[r_] = __builtin_amdgcn_exp2f(S[r_]);                                \
        _Pragma("unroll") for (int m_ = 0; m_ < 8; m_++)                           \
            W_[m_] = __builtin_bit_cast(unsigned,                                  \
                __builtin_amdgcn_cvt_pkrtz(p_[2*m_], p_[2*m_+1]));                 \
        _Pragma("unroll") for (int s2 = 0; s2 < 2; s2++) {                         \
            unsigned x0 = W_[4*s2+0], y0 = x0, x1 = W_[4*s2+1], y1 = x1;           \
            unsigned x2 = W_[4*s2+2], y2 = x2, x3 = W_[4*s2+3], y3 = x3;           \
            asm("v_permlane32_swap_b32 %0, %1" : "+v"(x0), "+v"(y0));              \
            asm("v_permlane32_swap_b32 %0, %1" : "+v"(x1), "+v"(y1));              \
            asm("v_permlane32_swap_b32 %0, %1" : "+v"(x2), "+v"(y2));              \
            asm("v_permlane32_swap_b32 %0, %1" : "+v"(x3), "+v"(y3));              \
            UWH8 bw_;                                                              \
            bw_.u[0] = hi ? x2 : x0;  bw_.u[1] = hi ? x3 : x1;                     \
            bw_.u[2] = hi ? y2 : y0;  bw_.u[3] = hi ? y3 : y1;                     \
            U4H8 vv_; vv_.u = VF[kt*2+s2];                                         \
            O = __builtin_amdgcn_mfma_f32_32x32x16_f16(vv_.h, bw_.h, O, 0,0,0);    \
        }                                                                          \
    }

#define ATTN_CHUNK(KF, VF)                                                         \
    _Pragma("unroll")                                                              \
    for (int kt = 0; kt < 2; kt++) {                                               \
        U4H8 ak_; ak_.u = KF[kt];                                                  \
        f16v S0 = __builtin_amdgcn_mfma_f32_32x32x16_f16(ak_.h, qf0.h, Zf, 0,0,0); \
        f16v S1 = __builtin_amdgcn_mfma_f32_32x32x16_f16(ak_.h, qf1.h, Zf, 0,0,0); \
        PROC_TILE(S0, O0, VF)                                                      \
        PROC_TILE(S1, O1, VF)                                                      \
    }

    for (int it = 0; it < 16; it += 2) {
        LOADC((start + it + 1) & 15, kb, vb)
        ATTN_CHUNK(ka, va)
        LOADC((start + it + 2) & 15, ka, va)   // wraps to start on last iter (redundant, harmless)
        ATTN_CHUNK(kb, vb)
    }
#undef ATTN_CHUNK
#undef PROC_TILE
#undef LOADC

    // split-K combine: O regs 0..7 are d = {0..3,8..11}+4*hi, reg 8 = L
    #pragma unroll
    for (int r = 0; r < 9; r++) {
        Osm[wave][0][lane][r] = O0[r];
        Osm[wave][1][lane][r] = O1[r];
    }
    __syncthreads();
    if (wave < 2) {
        const int qt2 = wave;
        float a[9];
        #pragma unroll
        for (int r = 0; r < 9; r++)
            a[r] = Osm[0][qt2][lane][r] + Osm[1][qt2][lane][r]
                 + Osm[2][qt2][lane][r] + Osm[3][qt2][lane][r];
        const float rinv = 1.f / a[8];
        h2 plo = __builtin_amdgcn_cvt_pkrtz(a[0]*rinv, a[1]*rinv);
        h2 phi = __builtin_amdgcn_cvt_pkrtz(a[2]*rinv, a[3]*rinv);
        h4 pk1 = (h4){plo.x, plo.y, phi.x, phi.y};
        plo = __builtin_amdgcn_cvt_pkrtz(a[4]*rinv, a[5]*rinv);
        phi = __builtin_amdgcn_cvt_pkrtz(a[6]*rinv, a[7]*rinv);
        h4 pk2 = (h4){plo.x, plo.y, phi.x, phi.y};
        const int b = head >> 2, hh = head & 3;
        const size_t q = (size_t)q0 + qt2*32 + l31;
        __fp16* dst = yh + ((size_t)b*TT + q)*CC + hh*DH + hi*4;   // d = hi*4
        *(h4*)dst = pk1;
        *(h4*)(dst + 8) = pk2;                                     // d = 8 + hi*4
    }
}

// ---------------- Kernel C: out = y @ w_proj^T + b_proj, D[r][o-quad] for float4 stores ----------------
// 512 blocks x 256 thr: block = 16 rows; wave w -> o-range [w*16, w*16+16)
__global__ __launch_bounds__(256) void proj_kernel(const __fp16* __restrict__ yh,
        const float* __restrict__ w, const float* __restrict__ bias,
        float* __restrict__ out) {
    const int t = threadIdx.x;
    const int wave = t >> 6, lane = t & 63;
    const int lq = lane & 15, g = lane >> 4;
    const int r0 = blockIdx.x*16;
    const int o0 = wave*16;

    // B-frag (y^T): lane holds y[r0+lq][s*16 + g*4 + j]
    h4 yb[4];
    const __fp16* yrow = yh + (size_t)(r0 + lq)*CC;
    #pragma unroll
    for (int s = 0; s < 4; s++) yb[s] = *(const h4*)(yrow + s*16 + g*4);

    float4 bv = *(const float4*)(bias + o0 + g*4);
    f4 acc = {bv.x, bv.y, bv.z, bv.w};
    #pragma unroll
    for (int s = 0; s < 4; s++) {
        // A-frag (w): lane holds w[o0+lq][s*16 + g*4 + j]
        float4 wv = *(const float4*)(w + (size_t)(o0 + lq)*CC + s*16 + g*4);
        h2 lo = __builtin_amdgcn_cvt_pkrtz(wv.x, wv.y);
        h2 hi = __builtin_amdgcn_cvt_pkrtz(wv.z, wv.w);
        h4 af = (h4){lo.x, lo.y, hi.x, hi.y};
        acc = __builtin_amdgcn_mfma_f32_16x16x16f16(af, yb[s], acc, 0, 0, 0);
    }
    // D: lane holds out[r0+lq][o0 + g*4 .. +3] -> coalesced float4
    *(float4*)(out + (size_t)(r0 + lq)*CC + o0 + g*4) = (float4){acc.x, acc.y, acc.z, acc.w};
}

extern "C" void kernel_launch(void* const* d_in, const int* in_sizes, int n_in,
                              void* d_out, int out_size, void* d_ws, size_t ws_size,
                              hipStream_t stream) {
    const float* x      = (const float*)d_in[0];
    const float* w_attn = (const float*)d_in[1];
    const float* b_attn = (const float*)d_in[2];
    const float* w_proj = (const float*)d_in[3];
    const float* b_proj = (const float*)d_in[4];
    float* out = (float*)d_out;

    const size_t headszQK = (size_t)BB*HH*TT*DH;   // Q,K: 512K halves each
    const size_t vtsz     = (size_t)BB*HH*TT*32;   // VT (d-expanded): 1M halves
    __fp16* Q   = (__fp16*)d_ws;
    __fp16* K   = Q + headszQK;
    __fp16* VT  = K + headszQK;
    __fp16* yh  = VT + vtsz;

    qkv_kernel<<<NROW/16, 256, 0, stream>>>(x, w_attn, b_attn, Q, K, VT);
    attn_kernel<<<BB*HH*(TT/64), 256, 0, stream>>>(Q, K, VT, yh);
    proj_kernel<<<NROW/16, 256, 0, stream>>>(yh, w_proj, b_proj, out);
}

// Round 6
// 88.713 us; speedup vs baseline: 1.1191x; 1.1191x over previous
//
#include <hip/hip_runtime.h>
#include <math.h>

#define BB 2
#define TT 4096
#define CC 64
#define HH 4
#define DH 16
#define NROW (BB*TT)                 // 8192
#define SCALE 0.36067376022224085f   // 0.25 * log2(e)

typedef __fp16 h4 __attribute__((ext_vector_type(4)));
typedef __fp16 h2 __attribute__((ext_vector_type(2)));
typedef __fp16 h8 __attribute__((ext_vector_type(8)));
typedef float  f4 __attribute__((ext_vector_type(4)));
typedef float  f16v __attribute__((ext_vector_type(16)));

union U4H8 { uint4 u; h8 h; };
union UWH8 { unsigned u[4]; h8 h; };

// ---------------- Kernel A: qkv GEMM, D[o][r] orientation for packed stores ----------------
// 512 blocks x 256 thr: block = 16 rows; wave w -> output tiles w*3..w*3+2 (of 12)
// Q,K: [bh][T][16] f16.
// VT k16-grouped, K-PERMUTED layout: [bh][chunk:64][sub:4][d:32][slot:16] f16
//   Within each 16-key sub-block, slot order holds keys
//   [0,1,2,3,8,9,10,11,4,5,6,7,12,13,14,15]  (involution).
//   This makes the PV B-operand EXACTLY the lane's own packed exp2(S) registers
//   (S D-layout: lane(l31,hi) holds keys {0-3,8-11}+4hi per 16-group; B needs
//   keys 8hi..8hi+7 -> permuted V columns align them), eliminating all
//   permlane-swaps/cndmask/movs in the attn inner loop.
//   d rows 0..15 = V^T; rows 16..31 = pad with rows 16 and 20 = 1.0 so the PV
//   32x32x16 MFMA accumulates L = sum(exp) into acc reg 8 of every lane.
__global__ __launch_bounds__(256) void qkv_kernel(const float* __restrict__ x,
        const float* __restrict__ w, const float* __restrict__ bias,
        __fp16* __restrict__ Q, __fp16* __restrict__ K, __fp16* __restrict__ VT) {
    __shared__ __fp16 smv[64][16];   // [h*16+d][t-col] staging for V transpose
    const int t = threadIdx.x;
    const int wave = t >> 6, lane = t & 63;
    const int lq = lane & 15, g = lane >> 4;
    const int r0 = blockIdx.x*16;
    const int b = r0 >> 12, tt0 = r0 & (TT-1);

    // B-frag (x^T): lane holds x[r0+lq][s*16 + g*4 + j]
    h4 xb[4];
    const float* xrow = x + (size_t)(r0 + lq)*CC;
    #pragma unroll
    for (int s = 0; s < 4; s++) {
        float4 xv = *(const float4*)(xrow + s*16 + g*4);
        h2 lo = __builtin_amdgcn_cvt_pkrtz(xv.x, xv.y);
        h2 hi = __builtin_amdgcn_cvt_pkrtz(xv.z, xv.w);
        xb[s] = (h4){lo.x, lo.y, hi.x, hi.y};
    }

    #pragma unroll
    for (int j = 0; j < 3; j++) {
        const int nt = wave*3 + j;       // tile: o-range [nt*16, nt*16+16)
        const int o0 = nt*16;
        const float sc = (nt < 4) ? SCALE : 1.0f;
        float4 bv = *(const float4*)(bias + o0 + g*4);
        f4 acc = {bv.x*sc, bv.y*sc, bv.z*sc, bv.w*sc};
        #pragma unroll
        for (int s = 0; s < 4; s++) {
            float4 wv = *(const float4*)(w + (size_t)(o0 + lq)*CC + s*16 + g*4);
            h2 lo = __builtin_amdgcn_cvt_pkrtz(wv.x*sc, wv.y*sc);
            h2 hi = __builtin_amdgcn_cvt_pkrtz(wv.z*sc, wv.w*sc);
            h4 af = (h4){lo.x, lo.y, hi.x, hi.y};
            acc = __builtin_amdgcn_mfma_f32_16x16x16f16(af, xb[s], acc, 0, 0, 0);
        }
        h2 plo = __builtin_amdgcn_cvt_pkrtz(acc.x, acc.y);
        h2 phi = __builtin_amdgcn_cvt_pkrtz(acc.z, acc.w);
        h4 pk = (h4){plo.x, plo.y, phi.x, phi.y};
        if (nt < 8) {
            const int part = nt >> 2, h = nt & 3;
            __fp16* dst = (part == 0) ? Q : K;
            *(h4*)(dst + ((size_t)(b*HH + h)*TT + tt0 + lq)*DH + g*4) = pk;
        } else {
            const int h = nt - 8;
            smv[h*16 + g*4 + 0][lq] = pk.x;
            smv[h*16 + g*4 + 1][lq] = pk.y;
            smv[h*16 + g*4 + 2][lq] = pk.z;
            smv[h*16 + g*4 + 3][lq] = pk.w;
        }
    }
    __syncthreads();
    if (t < 64) {                        // row (h,d): 16 t-cols = one k16 group = 32B
        const int h = t >> 4, d = t & 15;
        uint4 v0 = *(const uint4*)&smv[t][0];   // keys 0..7   (words k01,k23,k45,k67)
        uint4 v1 = *(const uint4*)&smv[t][8];   // keys 8..15  (words k89,kAB,kCD,kEF)
        // permuted slot order [0,1,2,3,8,9,10,11 | 4,5,6,7,12,13,14,15]
        uint4 pa = {v0.x, v0.y, v1.x, v1.y};    // slots 0..7
        uint4 pb = {v0.z, v0.w, v1.z, v1.w};    // slots 8..15
        // tt0 is a multiple of 16 -> all 16 cols land in sub = (tt0&63)>>4
        __fp16* dst = VT + (size_t)(b*HH + h)*TT*32
                        + (size_t)(tt0 >> 6)*2048           // chunk
                        + (size_t)((tt0 & 63) >> 4)*512     // sub
                        + (size_t)d*16;                     // d row
        *(uint4*)dst = pa;
        *(uint4*)(dst + 8) = pb;
        // pad row d+16: ones for d==0 (row 16) and d==4 (row 20), else zeros
        // (constant along k, so the key permutation is irrelevant here)
        const unsigned cb = (d == 0 || d == 4) ? 0x3C003C00u : 0u;
        const uint4 cv = {cb, cb, cb, cb};
        __fp16* dst2 = dst + 16*16;  // 16 rows down within the same sub-block
        *(uint4*)dst2 = cv;
        *(uint4*)(dst2 + 8) = cv;
    }
}

// ---------------- Kernel B: flash attention, 64 q-rows/block, native 32x32x16 MFMA ----------------
// 512 blocks x 256 thr.  TWO changes vs round 4/5:
//  (1) XCD-head affinity: head = blockIdx & 7 (was >>6).  With round-robin
//      block->XCD dispatch, XCD x gets exactly head x's 64 q-tile blocks; the
//      per-XCD K/VT working set drops from ~4-5MB (all heads, thrashing the 4MB
//      L2 -> measured 3x HBM re-fetch) to ~0.5MB (L2-resident after first touch).
//  (2) Swap-free P assembly: VT's key-permuted layout makes the PV B-operand the
//      lane's own packed exp2(S) registers -- no permlane32_swap, no cndmask.
// QK: D = K(32k x 16d) * Q(16d x 32q).  PV: A = V^T(32d x 16k, pad rows 16/20 =
// ones so acc reg 8 accumulates L = sum(exp) free).
__global__ __launch_bounds__(256) void attn_kernel(const __fp16* __restrict__ Q,
        const __fp16* __restrict__ K, const __fp16* __restrict__ VT,
        __fp16* __restrict__ yh) {
    __shared__ float Osm[4][2][64][9];   // [ksplit][qtile][lane][reg0..7, L]
    const int t = threadIdx.x;
    const int wave = t >> 6, lane = t & 63;
    const int l31 = lane & 31, hi = lane >> 5;
    const int head = blockIdx.x & 7;     // XCD-head affinity
    const int qt   = blockIdx.x >> 3;
    const int q0 = qt*64;
    const __fp16* Qh = Q  + (size_t)head*TT*DH;
    const __fp16* Kh = K  + (size_t)head*TT*DH;
    const __fp16* Vh = VT + (size_t)head*TT*32;

    // Q fragments (B-operand): col q = l31, d = hi*8 + j  -> 16B loads
    U4H8 qf0, qf1;
    qf0.u = *(const uint4*)(Qh + (size_t)(q0 + l31)*DH + hi*8);
    qf1.u = *(const uint4*)(Qh + (size_t)(q0 + 32 + l31)*DH + hi*8);

    const f16v Zf = {0.f,0.f,0.f,0.f,0.f,0.f,0.f,0.f,0.f,0.f,0.f,0.f,0.f,0.f,0.f,0.f};
    f16v O0 = Zf, O1 = Zf;

    // chunk-indexed base pointers within this wave's k-range
    const __fp16* kbase = Kh + (size_t)(wave*1024 + l31)*DH + hi*8;      // + c*1024 + kt*512
    // V A-frag: lane l31 = d row, slot = hi*8+j -> addr = d*16 + hi*8 (dense 1KB/wave)
    const __fp16* vbase = Vh + (size_t)(wave*16)*2048 + l31*16 + hi*8;   // + c*2048 + s*512

    const int start = (blockIdx.x*5 + wave*3) & 15;   // per-(block,wave) phase

    uint4 ka[2], va[4], kb[2], vb[4];

#define LOADC(c, KF, VF)                                                   \
    {  const size_t cc_ = (size_t)(c);                                     \
       _Pragma("unroll") for (int kt_ = 0; kt_ < 2; kt_++)                 \
           KF[kt_] = *(const uint4*)(kbase + cc_*1024 + kt_*512);          \
       _Pragma("unroll") for (int s_ = 0; s_ < 4; s_++)                    \
           VF[s_] = *(const uint4*)(vbase + cc_*2048 + s_*512);            \
    }

    LOADC(start, ka, va)

// W_[m] = packed f16 pair of exp2 of S regs (2m, 2m+1).  With the key-permuted
// VT layout, B-frag of 16-key group g is exactly W_[4g..4g+3] on every lane:
// hi=0 lanes hold keys {0-3,8-11} = permuted slots 0..7; hi=1 lanes hold keys
// {4-7,12-15} = permuted slots 8..15.  No cross-lane movement needed.
#define PROC_TILE(S, O, VF)                                                        \
    {   float p_[16]; unsigned W_[8];                                              \
        _Pragma("unroll") for (int r_ = 0; r_ < 16; r_++)                          \
            p_[r_] = __builtin_amdgcn_exp2f(S[r_]);                                \
        _Pragma("unroll") for (int m_ = 0; m_ < 8; m_++)                           \
            W_[m_] = __builtin_bit_cast(unsigned,                                  \
                __builtin_amdgcn_cvt_pkrtz(p_[2*m_], p_[2*m_+1]));                 \
        _Pragma("unroll") for (int s2 = 0; s2 < 2; s2++) {                         \
            UWH8 bw_;                                                              \
            bw_.u[0] = W_[4*s2+0];  bw_.u[1] = W_[4*s2+1];                         \
            bw_.u[2] = W_[4*s2+2];  bw_.u[3] = W_[4*s2+3];                         \
            U4H8 vv_; vv_.u = VF[kt*2+s2];                                         \
            O = __builtin_amdgcn_mfma_f32_32x32x16_f16(vv_.h, bw_.h, O, 0,0,0);    \
        }                                                                          \
    }

#define ATTN_CHUNK(KF, VF)                                                         \
    _Pragma("unroll")                                                              \
    for (int kt = 0; kt < 2; kt++) {                                               \
        U4H8 ak_; ak_.u = KF[kt];                                                  \
        f16v S0 = __builtin_amdgcn_mfma_f32_32x32x16_f16(ak_.h, qf0.h, Zf, 0,0,0); \
        f16v S1 = __builtin_amdgcn_mfma_f32_32x32x16_f16(ak_.h, qf1.h, Zf, 0,0,0); \
        PROC_TILE(S0, O0, VF)                                                      \
        PROC_TILE(S1, O1, VF)                                                      \
    }

    for (int it = 0; it < 16; it += 2) {
        LOADC((start + it + 1) & 15, kb, vb)
        ATTN_CHUNK(ka, va)
        LOADC((start + it + 2) & 15, ka, va)   // wraps to start on last iter (redundant, harmless)
        ATTN_CHUNK(kb, vb)
    }
#undef ATTN_CHUNK
#undef PROC_TILE
#undef LOADC

    // split-K combine: O regs 0..7 are d = {0..3,8..11}+4*hi, reg 8 = L
    #pragma unroll
    for (int r = 0; r < 9; r++) {
        Osm[wave][0][lane][r] = O0[r];
        Osm[wave][1][lane][r] = O1[r];
    }
    __syncthreads();
    if (wave < 2) {
        const int qt2 = wave;
        float a[9];
        #pragma unroll
        for (int r = 0; r < 9; r++)
            a[r] = Osm[0][qt2][lane][r] + Osm[1][qt2][lane][r]
                 + Osm[2][qt2][lane][r] + Osm[3][qt2][lane][r];
        const float rinv = 1.f / a[8];
        h2 plo = __builtin_amdgcn_cvt_pkrtz(a[0]*rinv, a[1]*rinv);
        h2 phi = __builtin_amdgcn_cvt_pkrtz(a[2]*rinv, a[3]*rinv);
        h4 pk1 = (h4){plo.x, plo.y, phi.x, phi.y};
        plo = __builtin_amdgcn_cvt_pkrtz(a[4]*rinv, a[5]*rinv);
        phi = __builtin_amdgcn_cvt_pkrtz(a[6]*rinv, a[7]*rinv);
        h4 pk2 = (h4){plo.x, plo.y, phi.x, phi.y};
        const int b = head >> 2, hh = head & 3;
        const size_t q = (size_t)q0 + qt2*32 + l31;
        __fp16* dst = yh + ((size_t)b*TT + q)*CC + hh*DH + hi*4;   // d = hi*4
        *(h4*)dst = pk1;
        *(h4*)(dst + 8) = pk2;                                     // d = 8 + hi*4
    }
}

// ---------------- Kernel C: out = y @ w_proj^T + b_proj, D[r][o-quad] for float4 stores ----------------
// 512 blocks x 256 thr: block = 16 rows; wave w -> o-range [w*16, w*16+16)
__global__ __launch_bounds__(256) void proj_kernel(const __fp16* __restrict__ yh,
        const float* __restrict__ w, const float* __restrict__ bias,
        float* __restrict__ out) {
    const int t = threadIdx.x;
    const int wave = t >> 6, lane = t & 63;
    const int lq = lane & 15, g = lane >> 4;
    const int r0 = blockIdx.x*16;
    const int o0 = wave*16;

    // B-frag (y^T): lane holds y[r0+lq][s*16 + g*4 + j]
    h4 yb[4];
    const __fp16* yrow = yh + (size_t)(r0 + lq)*CC;
    #pragma unroll
    for (int s = 0; s < 4; s++) yb[s] = *(const h4*)(yrow + s*16 + g*4);

    float4 bv = *(const float4*)(bias + o0 + g*4);
    f4 acc = {bv.x, bv.y, bv.z, bv.w};
    #pragma unroll
    for (int s = 0; s < 4; s++) {
        // A-frag (w): lane holds w[o0+lq][s*16 + g*4 + j]
        float4 wv = *(const float4*)(w + (size_t)(o0 + lq)*CC + s*16 + g*4);
        h2 lo = __builtin_amdgcn_cvt_pkrtz(wv.x, wv.y);
        h2 hi = __builtin_amdgcn_cvt_pkrtz(wv.z, wv.w);
        h4 af = (h4){lo.x, lo.y, hi.x, hi.y};
        acc = __builtin_amdgcn_mfma_f32_16x16x16f16(af, yb[s], acc, 0, 0, 0);
    }
    // D: lane holds out[r0+lq][o0 + g*4 .. +3] -> coalesced float4
    *(float4*)(out + (size_t)(r0 + lq)*CC + o0 + g*4) = (float4){acc.x, acc.y, acc.z, acc.w};
}

extern "C" void kernel_launch(void* const* d_in, const int* in_sizes, int n_in,
                              void* d_out, int out_size, void* d_ws, size_t ws_size,
                              hipStream_t stream) {
    const float* x      = (const float*)d_in[0];
    const float* w_attn = (const float*)d_in[1];
    const float* b_attn = (const float*)d_in[2];
    const float* w_proj = (const float*)d_in[3];
    const float* b_proj = (const float*)d_in[4];
    float* out = (float*)d_out;

    const size_t headszQK = (size_t)BB*HH*TT*DH;   // Q,K: 512K halves each
    const size_t vtsz     = (size_t)BB*HH*TT*32;   // VT (d-expanded): 1M halves
    __fp16* Q   = (__fp16*)d_ws;
    __fp16* K   = Q + headszQK;
    __fp16* VT  = K + headszQK;
    __fp16* yh  = VT + vtsz;

    qkv_kernel<<<NROW/16, 256, 0, stream>>>(x, w_attn, b_attn, Q, K, VT);
    attn_kernel<<<BB*HH*(TT/64), 256, 0, stream>>>(Q, K, VT, yh);
    proj_kernel<<<NROW/16, 256, 0, stream>>>(yh, w_proj, b_proj, out);
}